// Round 2
// baseline (1023.993 us; speedup 1.0000x reference)
//
#include <hip/hip_runtime.h>
#include <math.h>

#define NEG_SLOPE 0.2f

// ---------- GEMM1: h1 = x @ W1 [N,512]x[512,128], fused a_src1/a_dst1 ----------
__global__ __launch_bounds__(256) void gemm1_kernel(
    const float* __restrict__ x, const float* __restrict__ W,
    const float* __restrict__ att_src, const float* __restrict__ att_dst,
    float* __restrict__ h1, float* __restrict__ a_src, float* __restrict__ a_dst,
    int M)
{
  __shared__ float At[32][68];     // A tile transposed [k][row], pad 4 for b128 align
  __shared__ float Bs[32][128];
  const int tid = threadIdx.x;
  const int row0 = blockIdx.x * 64;
  const int tcol = (tid & 31) * 4;   // 0..124
  const int trow = (tid >> 5) * 8;   // 0..56
  float acc[8][4];
  #pragma unroll
  for (int i = 0; i < 8; i++)
    #pragma unroll
    for (int j = 0; j < 4; j++) acc[i][j] = 0.f;

  for (int k0 = 0; k0 < 512; k0 += 32) {
    #pragma unroll
    for (int i = 0; i < 2; ++i) {
      int idx = tid + i * 256;       // 0..511
      int r = idx >> 3;
      int kc = (idx & 7) << 2;
      float4 v = make_float4(0.f, 0.f, 0.f, 0.f);
      if (row0 + r < M) v = *(const float4*)&x[(size_t)(row0 + r) * 512 + k0 + kc];
      At[kc + 0][r] = v.x; At[kc + 1][r] = v.y; At[kc + 2][r] = v.z; At[kc + 3][r] = v.w;
    }
    #pragma unroll
    for (int i = 0; i < 4; ++i) {
      int idx = tid + i * 256;       // 0..1023
      int kk = idx >> 5;
      int cc = (idx & 31) << 2;
      *(float4*)&Bs[kk][cc] = *(const float4*)&W[(size_t)(k0 + kk) * 128 + cc];
    }
    __syncthreads();
    #pragma unroll
    for (int k = 0; k < 32; ++k) {
      float4 b = *(float4*)&Bs[k][tcol];
      float4 a0 = *(float4*)&At[k][trow];
      float4 a1 = *(float4*)&At[k][trow + 4];
      float av[8] = {a0.x, a0.y, a0.z, a0.w, a1.x, a1.y, a1.z, a1.w};
      float bv[4] = {b.x, b.y, b.z, b.w};
      #pragma unroll
      for (int i = 0; i < 8; i++)
        #pragma unroll
        for (int j = 0; j < 4; j++)
          acc[i][j] = fmaf(av[i], bv[j], acc[i][j]);
    }
    __syncthreads();
  }
  // epilogue: store h1, reduce a_src/a_dst per (row, head) over 4-lane groups
  float as1[4], ad1[4];
  #pragma unroll
  for (int j = 0; j < 4; j++) { as1[j] = att_src[tcol + j]; ad1[j] = att_dst[tcol + j]; }
  const int head = tcol >> 4;
  #pragma unroll
  for (int i = 0; i < 8; i++) {
    int r = row0 + trow + i;
    float ps = acc[i][0]*as1[0] + acc[i][1]*as1[1] + acc[i][2]*as1[2] + acc[i][3]*as1[3];
    float pd = acc[i][0]*ad1[0] + acc[i][1]*ad1[1] + acc[i][2]*ad1[2] + acc[i][3]*ad1[3];
    ps += __shfl_xor(ps, 1); ps += __shfl_xor(ps, 2);
    pd += __shfl_xor(pd, 1); pd += __shfl_xor(pd, 2);
    if (r < M) {
      float4 o = make_float4(acc[i][0], acc[i][1], acc[i][2], acc[i][3]);
      *(float4*)&h1[(size_t)r * 128 + tcol] = o;
      if ((tid & 3) == 0) { a_src[r * 8 + head] = ps; a_dst[r * 8 + head] = pd; }
    }
  }
}

// ---------- Counting sort of edges by dst ----------
__global__ __launch_bounds__(256) void hist_kernel(
    const int* __restrict__ ei, int E, int ET, int* __restrict__ cnt)
{
  int e = blockIdx.x * 256 + threadIdx.x;
  if (e >= ET) return;
  int dst = (e < E) ? ei[E + e] : e - E;     // self-loops appended
  atomicAdd(&cnt[dst], 1);
}

__global__ __launch_bounds__(256) void scan_bsum(
    const int* __restrict__ cnt, int* __restrict__ bsum, int M)
{
  __shared__ int sm[256];
  int i = blockIdx.x * 256 + threadIdx.x;
  sm[threadIdx.x] = (i < M) ? cnt[i] : 0;
  __syncthreads();
  for (int o = 128; o; o >>= 1) {
    if (threadIdx.x < o) sm[threadIdx.x] += sm[threadIdx.x + o];
    __syncthreads();
  }
  if (threadIdx.x == 0) bsum[blockIdx.x] = sm[0];
}

__global__ __launch_bounds__(512) void scan_boff(
    const int* __restrict__ bsum, int* __restrict__ boff, int NB)
{
  __shared__ int sm[512];
  int t = threadIdx.x;
  int v = (t < NB) ? bsum[t] : 0;
  sm[t] = v; __syncthreads();
  #pragma unroll
  for (int o = 1; o < 512; o <<= 1) {
    int add = (t >= o) ? sm[t - o] : 0;
    __syncthreads();
    sm[t] += add;
    __syncthreads();
  }
  boff[t] = sm[t] - v;                        // exclusive
}

__global__ __launch_bounds__(256) void scan_final(
    const int* __restrict__ cnt, const int* __restrict__ boff,
    int* __restrict__ startp, int* __restrict__ cursor, int M)
{
  __shared__ int sm[256];
  int t = threadIdx.x;
  int i = blockIdx.x * 256 + t;
  int v = (i < M) ? cnt[i] : 0;
  sm[t] = v; __syncthreads();
  #pragma unroll
  for (int o = 1; o < 256; o <<= 1) {
    int add = (t >= o) ? sm[t - o] : 0;
    __syncthreads();
    sm[t] += add;
    __syncthreads();
  }
  int excl = sm[t] - v + boff[blockIdx.x];
  if (i < M) {
    startp[i] = excl;
    cursor[i] = excl;
    if (i == M - 1) startp[M] = excl + v;
  }
}

__global__ __launch_bounds__(256) void scatter_kernel(
    const int* __restrict__ ei, int E, int ET,
    int* __restrict__ cursor, int* __restrict__ ssrc)
{
  int e = blockIdx.x * 256 + threadIdx.x;
  if (e >= ET) return;
  int src, dst;
  if (e < E) { src = ei[e]; dst = ei[E + e]; }
  else { src = e - E; dst = src; }
  int pos = atomicAdd(&cursor[dst], 1);
  ssrc[pos] = src;
}

// ---------- Layer-1 aggregate: 128 thr/node, fused normalize+bias+ELU ----------
__global__ __launch_bounds__(256) void agg1_kernel(
    const int* __restrict__ startp, const int* __restrict__ ssrc,
    const float* __restrict__ a_s, const float* __restrict__ a_d,
    const float* __restrict__ h1, const float* __restrict__ b1,
    float* __restrict__ h1e, int M)
{
  int n = blockIdx.x * 2 + (threadIdx.x >> 7);
  if (n >= M) return;
  int c = threadIdx.x & 127;
  int h = c >> 4;
  float ad = a_d[n * 8 + h];
  int jb = startp[n], je = startp[n + 1];
  float acc = 0.f, ssum = 0.f;
  int j = jb;
  for (; j + 1 < je; j += 2) {                 // 2-way MLP for the gathers
    int s0 = ssrc[j], s1 = ssrc[j + 1];
    float e0 = a_s[s0 * 8 + h] + ad;
    float e1 = a_s[s1 * 8 + h] + ad;
    e0 = e0 > 0.f ? e0 : NEG_SLOPE * e0;
    e1 = e1 > 0.f ? e1 : NEG_SLOPE * e1;
    float x0 = __expf(e0), x1 = __expf(e1);
    float g0 = h1[(size_t)s0 * 128 + c];
    float g1 = h1[(size_t)s1 * 128 + c];
    acc = fmaf(x0, g0, acc);
    acc = fmaf(x1, g1, acc);
    ssum += x0 + x1;
  }
  if (j < je) {
    int s0 = ssrc[j];
    float e0 = a_s[s0 * 8 + h] + ad;
    e0 = e0 > 0.f ? e0 : NEG_SLOPE * e0;
    float x0 = __expf(e0);
    acc = fmaf(x0, h1[(size_t)s0 * 128 + c], acc);
    ssum += x0;
  }
  float v = acc / ssum + b1[c];                // self-loop guarantees ssum > 0
  h1e[(size_t)n * 128 + c] = v > 0.f ? v : expm1f(v);
}

// ---------- GEMM2: h2 = h1e @ W2 [N,128]x[128,40], fused a2 dots ----------
__global__ __launch_bounds__(256) void gemm2_kernel(
    const float* __restrict__ h, const float* __restrict__ W2,
    const float* __restrict__ att_src, const float* __restrict__ att_dst,
    float* __restrict__ h2, float* __restrict__ a2s, float* __restrict__ a2d,
    int M)
{
  __shared__ float W2s[128 * 40];   // 20 KB, whole W2
  __shared__ float hs[4][128];
  const int tid = threadIdx.x;
  const int lane = tid & 63;
  const int w = tid >> 6;
  for (int i = tid; i < 128 * 40; i += 256) W2s[i] = W2[i];
  float asv = (lane < 40) ? att_src[lane] : 0.f;
  float adv = (lane < 40) ? att_dst[lane] : 0.f;
  __syncthreads();
  for (int r0 = blockIdx.x * 4; r0 < M; r0 += gridDim.x * 4) {
    #pragma unroll
    for (int i = 0; i < 2; ++i) {
      int idx = tid + i * 256;
      int r = r0 + (idx >> 7);
      hs[idx >> 7][idx & 127] = (r < M) ? h[(size_t)r * 128 + (idx & 127)] : 0.f;
    }
    __syncthreads();
    const int row = r0 + w;
    float acc = 0.f;
    if (lane < 40) {
      #pragma unroll 8
      for (int k = 0; k < 128; ++k) acc = fmaf(hs[w][k], W2s[k * 40 + lane], acc);
    }
    float ps = acc * asv, pd = acc * adv;
    #pragma unroll
    for (int off = 32; off; off >>= 1) { ps += __shfl_xor(ps, off); pd += __shfl_xor(pd, off); }
    if (row < M) {
      if (lane < 40) h2[(size_t)row * 40 + lane] = acc;
      if (lane == 0) { a2s[row] = ps; a2d[row] = pd; }
    }
    __syncthreads();
  }
}

// ---------- Layer-2 aggregate: 64 thr/node, fused normalize+bias+log_softmax ----------
__global__ __launch_bounds__(256) void agg2_kernel(
    const int* __restrict__ startp, const int* __restrict__ ssrc,
    const float* __restrict__ a2s, const float* __restrict__ a2d,
    const float* __restrict__ h2, const float* __restrict__ b2,
    float* __restrict__ outp, int M)
{
  int n = blockIdx.x * 4 + (threadIdx.x >> 6);
  if (n >= M) return;
  int lane = threadIdx.x & 63;
  bool act = lane < 40;
  float ad = a2d[n];
  int jb = startp[n], je = startp[n + 1];
  float acc = 0.f, ssum = 0.f;
  int j = jb;
  for (; j + 1 < je; j += 2) {
    int s0 = ssrc[j], s1 = ssrc[j + 1];
    float e0 = a2s[s0] + ad;
    float e1 = a2s[s1] + ad;
    e0 = e0 > 0.f ? e0 : NEG_SLOPE * e0;
    e1 = e1 > 0.f ? e1 : NEG_SLOPE * e1;
    float x0 = __expf(e0), x1 = __expf(e1);
    float g0 = act ? h2[(size_t)s0 * 40 + lane] : 0.f;
    float g1 = act ? h2[(size_t)s1 * 40 + lane] : 0.f;
    acc = fmaf(x0, g0, acc);
    acc = fmaf(x1, g1, acc);
    ssum += x0 + x1;
  }
  if (j < je) {
    int s0 = ssrc[j];
    float e0 = a2s[s0] + ad;
    e0 = e0 > 0.f ? e0 : NEG_SLOPE * e0;
    float x0 = __expf(e0);
    if (act) acc = fmaf(x0, h2[(size_t)s0 * 40 + lane], acc);
    ssum += x0;
  }
  float v = act ? acc / ssum + b2[lane] : -1e30f;
  // log_softmax over the 40 classes (full-precision exp/log; negligible cost)
  float m = v;
  #pragma unroll
  for (int o = 32; o; o >>= 1) m = fmaxf(m, __shfl_xor(m, o));
  float ex = act ? expf(v - m) : 0.f;
  float s = ex;
  #pragma unroll
  for (int o = 32; o; o >>= 1) s += __shfl_xor(s, o);
  if (act) outp[(size_t)n * 40 + lane] = v - m - logf(s);
}

extern "C" void kernel_launch(void* const* d_in, const int* in_sizes, int n_in,
                              void* d_out, int out_size, void* d_ws, size_t ws_size,
                              hipStream_t stream)
{
  const float* x   = (const float*)d_in[0];
  const int*   ei  = (const int*)d_in[1];
  const float* W1  = (const float*)d_in[2];
  const float* as1 = (const float*)d_in[3];
  const float* ad1 = (const float*)d_in[4];
  const float* b1  = (const float*)d_in[5];
  const float* W2  = (const float*)d_in[6];
  const float* as2 = (const float*)d_in[7];
  const float* ad2 = (const float*)d_in[8];
  const float* b2  = (const float*)d_in[9];
  float* outp = (float*)d_out;

  const int M  = in_sizes[0] / 512;    // 100000
  const int E  = in_sizes[1] / 2;      // 1600000
  const int ET = E + M;                // + self loops
  const int NB = (M + 255) / 256;      // scan blocks (391)

  float* ws = (float*)d_ws;
  float* h1   = ws;                         // M*128
  float* a_s1 = h1 + (size_t)M * 128;       // M*8
  float* a_d1 = a_s1 + (size_t)M * 8;       // M*8
  float* h1e  = a_d1 + (size_t)M * 8;       // M*128
  float* h2   = h1e + (size_t)M * 128;      // M*40
  float* a2s  = h2 + (size_t)M * 40;        // M
  float* a2d  = a2s + M;                    // M
  int* cnt    = (int*)(a2d + M);            // M
  int* startp = cnt + M;                    // M+1
  int* cursor = startp + (M + 1);           // M
  int* bsum   = cursor + M;                 // NB
  int* boff   = bsum + NB;                  // 512
  int* ssrc   = boff + 512;                 // ET

  hipMemsetAsync(cnt, 0, (size_t)M * sizeof(int), stream);

  // edge sort by dst (reused by both layers)
  hist_kernel<<<(ET + 255) / 256, 256, 0, stream>>>(ei, E, ET, cnt);
  scan_bsum<<<NB, 256, 0, stream>>>(cnt, bsum, M);
  scan_boff<<<1, 512, 0, stream>>>(bsum, boff, NB);
  scan_final<<<NB, 256, 0, stream>>>(cnt, boff, startp, cursor, M);
  scatter_kernel<<<(ET + 255) / 256, 256, 0, stream>>>(ei, E, ET, cursor, ssrc);

  // layer 1
  gemm1_kernel<<<(M + 63) / 64, 256, 0, stream>>>(x, W1, as1, ad1, h1, a_s1, a_d1, M);
  agg1_kernel<<<(M + 1) / 2, 256, 0, stream>>>(startp, ssrc, a_s1, a_d1, h1, b1, h1e, M);

  // layer 2
  gemm2_kernel<<<1024, 256, 0, stream>>>(h1e, W2, as2, ad2, h2, a2s, a2d, M);
  agg2_kernel<<<(M + 3) / 4, 256, 0, stream>>>(startp, ssrc, a2s, a2d, h2, b2, outp, M);
}

// Round 3
// 843.388 us; speedup vs baseline: 1.2141x; 1.2141x over previous
//
#include <hip/hip_runtime.h>
#include <hip/hip_fp16.h>
#include <math.h>

#define NEG_SLOPE 0.2f

// ---------- GEMM1: h1 = x @ W1 [N,512]x[512,128] fp32 compute, fp16 store,
//            fused a_src1/a_dst1 ----------
__global__ __launch_bounds__(256) void gemm1_kernel(
    const float* __restrict__ x, const float* __restrict__ W,
    const float* __restrict__ att_src, const float* __restrict__ att_dst,
    __half* __restrict__ h1, float* __restrict__ a_src, float* __restrict__ a_dst,
    int M)
{
  __shared__ float At[32][68];     // A tile transposed [k][row]
  __shared__ float Bs[32][128];
  const int tid = threadIdx.x;
  const int row0 = blockIdx.x * 64;
  const int tcol = (tid & 31) * 4;   // 0..124
  const int trow = (tid >> 5) * 8;   // 0..56
  float acc[8][4];
  #pragma unroll
  for (int i = 0; i < 8; i++)
    #pragma unroll
    for (int j = 0; j < 4; j++) acc[i][j] = 0.f;

  for (int k0 = 0; k0 < 512; k0 += 32) {
    #pragma unroll
    for (int i = 0; i < 2; ++i) {
      int idx = tid + i * 256;       // 0..511
      int r = idx >> 3;
      int kc = (idx & 7) << 2;
      float4 v = make_float4(0.f, 0.f, 0.f, 0.f);
      if (row0 + r < M) v = *(const float4*)&x[(size_t)(row0 + r) * 512 + k0 + kc];
      At[kc + 0][r] = v.x; At[kc + 1][r] = v.y; At[kc + 2][r] = v.z; At[kc + 3][r] = v.w;
    }
    #pragma unroll
    for (int i = 0; i < 4; ++i) {
      int idx = tid + i * 256;       // 0..1023
      int kk = idx >> 5;
      int cc = (idx & 31) << 2;
      *(float4*)&Bs[kk][cc] = *(const float4*)&W[(size_t)(k0 + kk) * 128 + cc];
    }
    __syncthreads();
    #pragma unroll
    for (int k = 0; k < 32; ++k) {
      float4 b = *(float4*)&Bs[k][tcol];
      float4 a0 = *(float4*)&At[k][trow];
      float4 a1 = *(float4*)&At[k][trow + 4];
      float av[8] = {a0.x, a0.y, a0.z, a0.w, a1.x, a1.y, a1.z, a1.w};
      float bv[4] = {b.x, b.y, b.z, b.w};
      #pragma unroll
      for (int i = 0; i < 8; i++)
        #pragma unroll
        for (int j = 0; j < 4; j++)
          acc[i][j] = fmaf(av[i], bv[j], acc[i][j]);
    }
    __syncthreads();
  }
  float as1[4], ad1[4];
  #pragma unroll
  for (int j = 0; j < 4; j++) { as1[j] = att_src[tcol + j]; ad1[j] = att_dst[tcol + j]; }
  const int head = tcol >> 4;
  #pragma unroll
  for (int i = 0; i < 8; i++) {
    int r = row0 + trow + i;
    float ps = acc[i][0]*as1[0] + acc[i][1]*as1[1] + acc[i][2]*as1[2] + acc[i][3]*as1[3];
    float pd = acc[i][0]*ad1[0] + acc[i][1]*ad1[1] + acc[i][2]*ad1[2] + acc[i][3]*ad1[3];
    ps += __shfl_xor(ps, 1); ps += __shfl_xor(ps, 2);
    pd += __shfl_xor(pd, 1); pd += __shfl_xor(pd, 2);
    if (r < M) {
      __half2 p0 = __floats2half2_rn(acc[i][0], acc[i][1]);
      __half2 p1 = __floats2half2_rn(acc[i][2], acc[i][3]);
      uint2 u = make_uint2(*(unsigned int*)&p0, *(unsigned int*)&p1);
      *(uint2*)&h1[(size_t)r * 128 + tcol] = u;
      if ((tid & 3) == 0) { a_src[r * 8 + head] = ps; a_dst[r * 8 + head] = pd; }
    }
  }
}

// ---------- Counting sort of edges by dst ----------
__global__ __launch_bounds__(256) void hist_kernel(
    const int* __restrict__ ei, int E, int ET, int* __restrict__ cnt)
{
  int e = blockIdx.x * 256 + threadIdx.x;
  if (e >= ET) return;
  int dst = (e < E) ? ei[E + e] : e - E;     // self-loops appended
  atomicAdd(&cnt[dst], 1);
}

__global__ __launch_bounds__(256) void scan_bsum(
    const int* __restrict__ cnt, int* __restrict__ bsum, int M)
{
  __shared__ int sm[256];
  int i = blockIdx.x * 256 + threadIdx.x;
  sm[threadIdx.x] = (i < M) ? cnt[i] : 0;
  __syncthreads();
  for (int o = 128; o; o >>= 1) {
    if (threadIdx.x < o) sm[threadIdx.x] += sm[threadIdx.x + o];
    __syncthreads();
  }
  if (threadIdx.x == 0) bsum[blockIdx.x] = sm[0];
}

__global__ __launch_bounds__(512) void scan_boff(
    const int* __restrict__ bsum, int* __restrict__ boff, int NB)
{
  __shared__ int sm[512];
  int t = threadIdx.x;
  int v = (t < NB) ? bsum[t] : 0;
  sm[t] = v; __syncthreads();
  #pragma unroll
  for (int o = 1; o < 512; o <<= 1) {
    int add = (t >= o) ? sm[t - o] : 0;
    __syncthreads();
    sm[t] += add;
    __syncthreads();
  }
  boff[t] = sm[t] - v;                        // exclusive
}

__global__ __launch_bounds__(256) void scan_final(
    const int* __restrict__ cnt, const int* __restrict__ boff,
    int* __restrict__ startp, int* __restrict__ cursor, int M)
{
  __shared__ int sm[256];
  int t = threadIdx.x;
  int i = blockIdx.x * 256 + t;
  int v = (i < M) ? cnt[i] : 0;
  sm[t] = v; __syncthreads();
  #pragma unroll
  for (int o = 1; o < 256; o <<= 1) {
    int add = (t >= o) ? sm[t - o] : 0;
    __syncthreads();
    sm[t] += add;
    __syncthreads();
  }
  int excl = sm[t] - v + boff[blockIdx.x];
  if (i < M) {
    startp[i] = excl;
    cursor[i] = excl;
    if (i == M - 1) startp[M] = excl + v;
  }
}

__global__ __launch_bounds__(256) void scatter_kernel(
    const int* __restrict__ ei, int E, int ET,
    int* __restrict__ cursor, int* __restrict__ ssrc)
{
  int e = blockIdx.x * 256 + threadIdx.x;
  if (e >= ET) return;
  int src, dst;
  if (e < E) { src = ei[e]; dst = ei[E + e]; }
  else { src = e - E; dst = src; }
  int pos = atomicAdd(&cursor[dst], 1);
  ssrc[pos] = src;
}

// ---------- Layer-1 aggregate: 64 thr/node, 2 ch/thread (half2),
//            fused normalize+bias+ELU, fp16 out ----------
__global__ __launch_bounds__(256) void agg1_kernel(
    const int* __restrict__ startp, const int* __restrict__ ssrc,
    const float* __restrict__ a_s, const float* __restrict__ a_d,
    const __half* __restrict__ h1, const float* __restrict__ b1,
    __half* __restrict__ h1e, int M)
{
  int n = blockIdx.x * 4 + (threadIdx.x >> 6);
  if (n >= M) return;
  const int lane = threadIdx.x & 63;
  const int hd = lane >> 3;                  // channels (2*lane, 2*lane+1) -> head
  const __half2* hp = (const __half2*)h1;
  float ad = a_d[n * 8 + hd];
  int jb = startp[n], je = startp[n + 1];
  float acc0 = 0.f, acc1 = 0.f, ssum = 0.f;
  int j = jb;
  for (; j + 3 < je; j += 4) {               // 4-way MLP for the gathers
    int s0 = ssrc[j], s1 = ssrc[j+1], s2 = ssrc[j+2], s3 = ssrc[j+3];
    float e0 = a_s[s0 * 8 + hd] + ad;
    float e1 = a_s[s1 * 8 + hd] + ad;
    float e2 = a_s[s2 * 8 + hd] + ad;
    float e3 = a_s[s3 * 8 + hd] + ad;
    __half2 g0 = hp[(size_t)s0 * 64 + lane];
    __half2 g1 = hp[(size_t)s1 * 64 + lane];
    __half2 g2 = hp[(size_t)s2 * 64 + lane];
    __half2 g3 = hp[(size_t)s3 * 64 + lane];
    e0 = e0 > 0.f ? e0 : NEG_SLOPE * e0;
    e1 = e1 > 0.f ? e1 : NEG_SLOPE * e1;
    e2 = e2 > 0.f ? e2 : NEG_SLOPE * e2;
    e3 = e3 > 0.f ? e3 : NEG_SLOPE * e3;
    float x0 = __expf(e0), x1 = __expf(e1), x2 = __expf(e2), x3 = __expf(e3);
    float2 f0 = __half22float2(g0), f1 = __half22float2(g1);
    float2 f2 = __half22float2(g2), f3 = __half22float2(g3);
    acc0 = fmaf(x0, f0.x, acc0); acc1 = fmaf(x0, f0.y, acc1);
    acc0 = fmaf(x1, f1.x, acc0); acc1 = fmaf(x1, f1.y, acc1);
    acc0 = fmaf(x2, f2.x, acc0); acc1 = fmaf(x2, f2.y, acc1);
    acc0 = fmaf(x3, f3.x, acc0); acc1 = fmaf(x3, f3.y, acc1);
    ssum += (x0 + x1) + (x2 + x3);
  }
  for (; j < je; ++j) {
    int s0 = ssrc[j];
    float e0 = a_s[s0 * 8 + hd] + ad;
    e0 = e0 > 0.f ? e0 : NEG_SLOPE * e0;
    float x0 = __expf(e0);
    float2 f0 = __half22float2(hp[(size_t)s0 * 64 + lane]);
    acc0 = fmaf(x0, f0.x, acc0); acc1 = fmaf(x0, f0.y, acc1);
    ssum += x0;
  }
  float2 bv = *(const float2*)&b1[lane * 2];
  float v0 = acc0 / ssum + bv.x;             // self-loop guarantees ssum > 0
  float v1 = acc1 / ssum + bv.y;
  v0 = v0 > 0.f ? v0 : expm1f(v0);
  v1 = v1 > 0.f ? v1 : expm1f(v1);
  ((__half2*)h1e)[(size_t)n * 64 + lane] = __floats2half2_rn(v0, v1);
}

// ---------- GEMM2: h2 = h1e @ W2 [N,128]x[128,40], fused a2 dots, fp16 out ----------
__global__ __launch_bounds__(256) void gemm2_kernel(
    const __half* __restrict__ h, const float* __restrict__ W2,
    const float* __restrict__ att_src, const float* __restrict__ att_dst,
    __half* __restrict__ h2, float* __restrict__ a2s, float* __restrict__ a2d,
    int M)
{
  __shared__ float W2s[128 * 40];   // 20 KB, whole W2
  __shared__ float hs[4][128];
  const int tid = threadIdx.x;
  const int lane = tid & 63;
  const int w = tid >> 6;
  const __half2* hp = (const __half2*)h;
  for (int i = tid; i < 128 * 40; i += 256) W2s[i] = W2[i];
  float asv = (lane < 40) ? att_src[lane] : 0.f;
  float adv = (lane < 40) ? att_dst[lane] : 0.f;
  __syncthreads();
  for (int r0 = blockIdx.x * 4; r0 < M; r0 += gridDim.x * 4) {
    {
      int r = r0 + (tid >> 6);
      int cp = tid & 63;
      float2 f = make_float2(0.f, 0.f);
      if (r < M) f = __half22float2(hp[(size_t)r * 64 + cp]);
      hs[tid >> 6][cp * 2] = f.x; hs[tid >> 6][cp * 2 + 1] = f.y;
    }
    __syncthreads();
    const int row = r0 + w;
    float acc = 0.f;
    if (lane < 40) {
      #pragma unroll 8
      for (int k = 0; k < 128; ++k) acc = fmaf(hs[w][k], W2s[k * 40 + lane], acc);
    }
    float ps = acc * asv, pd = acc * adv;
    #pragma unroll
    for (int off = 32; off; off >>= 1) { ps += __shfl_xor(ps, off); pd += __shfl_xor(pd, off); }
    if (row < M) {
      if (lane < 40) h2[(size_t)row * 40 + lane] = __float2half_rn(acc);
      if (lane == 0) { a2s[row] = ps; a2d[row] = pd; }
    }
    __syncthreads();
  }
}

// ---------- Layer-2 aggregate: 32 lanes/node, 2 ch/thread,
//            fused normalize+bias+log_softmax ----------
__global__ __launch_bounds__(256) void agg2_kernel(
    const int* __restrict__ startp, const int* __restrict__ ssrc,
    const float* __restrict__ a2s, const float* __restrict__ a2d,
    const __half* __restrict__ h2, const float* __restrict__ b2,
    float* __restrict__ outp, int M)
{
  int n = blockIdx.x * 8 + (threadIdx.x >> 5);
  if (n >= M) return;
  const int l = threadIdx.x & 31;
  const bool act = l < 20;
  const __half2* hp = (const __half2*)h2;    // row = 20 half2
  float ad = a2d[n];
  int jb = startp[n], je = startp[n + 1];
  float acc0 = 0.f, acc1 = 0.f, ssum = 0.f;
  __half2 z2 = __floats2half2_rn(0.f, 0.f);
  int j = jb;
  for (; j + 3 < je; j += 4) {
    int s0 = ssrc[j], s1 = ssrc[j+1], s2 = ssrc[j+2], s3 = ssrc[j+3];
    float e0 = a2s[s0] + ad;
    float e1 = a2s[s1] + ad;
    float e2 = a2s[s2] + ad;
    float e3 = a2s[s3] + ad;
    __half2 g0 = act ? hp[(size_t)s0 * 20 + l] : z2;
    __half2 g1 = act ? hp[(size_t)s1 * 20 + l] : z2;
    __half2 g2 = act ? hp[(size_t)s2 * 20 + l] : z2;
    __half2 g3 = act ? hp[(size_t)s3 * 20 + l] : z2;
    e0 = e0 > 0.f ? e0 : NEG_SLOPE * e0;
    e1 = e1 > 0.f ? e1 : NEG_SLOPE * e1;
    e2 = e2 > 0.f ? e2 : NEG_SLOPE * e2;
    e3 = e3 > 0.f ? e3 : NEG_SLOPE * e3;
    float x0 = __expf(e0), x1 = __expf(e1), x2 = __expf(e2), x3 = __expf(e3);
    float2 f0 = __half22float2(g0), f1 = __half22float2(g1);
    float2 f2 = __half22float2(g2), f3 = __half22float2(g3);
    acc0 = fmaf(x0, f0.x, acc0); acc1 = fmaf(x0, f0.y, acc1);
    acc0 = fmaf(x1, f1.x, acc0); acc1 = fmaf(x1, f1.y, acc1);
    acc0 = fmaf(x2, f2.x, acc0); acc1 = fmaf(x2, f2.y, acc1);
    acc0 = fmaf(x3, f3.x, acc0); acc1 = fmaf(x3, f3.y, acc1);
    ssum += (x0 + x1) + (x2 + x3);
  }
  for (; j < je; ++j) {
    int s0 = ssrc[j];
    float e0 = a2s[s0] + ad;
    e0 = e0 > 0.f ? e0 : NEG_SLOPE * e0;
    float x0 = __expf(e0);
    float2 f0 = __half22float2(act ? hp[(size_t)s0 * 20 + l] : z2);
    acc0 = fmaf(x0, f0.x, acc0); acc1 = fmaf(x0, f0.y, acc1);
    ssum += x0;
  }
  float v0 = act ? acc0 / ssum + b2[l * 2]     : -1e30f;
  float v1 = act ? acc1 / ssum + b2[l * 2 + 1] : -1e30f;
  // log_softmax over 40 classes held as 2 values x 20 lanes (within 32-lane group)
  float m = fmaxf(v0, v1);
  #pragma unroll
  for (int o = 16; o; o >>= 1) m = fmaxf(m, __shfl_xor(m, o));
  float ex = act ? expf(v0 - m) + expf(v1 - m) : 0.f;
  #pragma unroll
  for (int o = 16; o; o >>= 1) ex += __shfl_xor(ex, o);
  float lg = m + logf(ex);
  if (act) *(float2*)&outp[(size_t)n * 40 + l * 2] = make_float2(v0 - lg, v1 - lg);
}

extern "C" void kernel_launch(void* const* d_in, const int* in_sizes, int n_in,
                              void* d_out, int out_size, void* d_ws, size_t ws_size,
                              hipStream_t stream)
{
  const float* x   = (const float*)d_in[0];
  const int*   ei  = (const int*)d_in[1];
  const float* W1  = (const float*)d_in[2];
  const float* as1 = (const float*)d_in[3];
  const float* ad1 = (const float*)d_in[4];
  const float* b1  = (const float*)d_in[5];
  const float* W2  = (const float*)d_in[6];
  const float* as2 = (const float*)d_in[7];
  const float* ad2 = (const float*)d_in[8];
  const float* b2  = (const float*)d_in[9];
  float* outp = (float*)d_out;

  const int M  = in_sizes[0] / 512;    // 100000
  const int E  = in_sizes[1] / 2;      // 1600000
  const int ET = E + M;                // + self loops
  const int NB = (M + 255) / 256;      // scan blocks (391)

  __half* h1  = (__half*)d_ws;              // M*128 fp16
  __half* h1e = h1 + (size_t)M * 128;       // M*128 fp16
  __half* h2  = h1e + (size_t)M * 128;      // M*40 fp16
  float* a_s1 = (float*)(h2 + (size_t)M * 40);
  float* a_d1 = a_s1 + (size_t)M * 8;
  float* a2s  = a_d1 + (size_t)M * 8;
  float* a2d  = a2s + M;
  int* cnt    = (int*)(a2d + M);            // M
  int* startp = cnt + M;                    // M+1
  int* cursor = startp + (M + 1);           // M
  int* bsum   = cursor + M;                 // NB
  int* boff   = bsum + NB;                  // 512
  int* ssrc   = boff + 512;                 // ET

  hipMemsetAsync(cnt, 0, (size_t)M * sizeof(int), stream);

  // edge sort by dst (reused by both layers)
  hist_kernel<<<(ET + 255) / 256, 256, 0, stream>>>(ei, E, ET, cnt);
  scan_bsum<<<NB, 256, 0, stream>>>(cnt, bsum, M);
  scan_boff<<<1, 512, 0, stream>>>(bsum, boff, NB);
  scan_final<<<NB, 256, 0, stream>>>(cnt, boff, startp, cursor, M);
  scatter_kernel<<<(ET + 255) / 256, 256, 0, stream>>>(ei, E, ET, cursor, ssrc);

  // layer 1
  gemm1_kernel<<<(M + 63) / 64, 256, 0, stream>>>(x, W1, as1, ad1, h1, a_s1, a_d1, M);
  agg1_kernel<<<(M + 3) / 4, 256, 0, stream>>>(startp, ssrc, a_s1, a_d1, h1, b1, h1e, M);

  // layer 2
  gemm2_kernel<<<1024, 256, 0, stream>>>(h1e, W2, as2, ad2, h2, a2s, a2d, M);
  agg2_kernel<<<(M + 7) / 8, 256, 0, stream>>>(startp, ssrc, a2s, a2d, h2, b2, outp, M);
}

// Round 4
// 798.336 us; speedup vs baseline: 1.2827x; 1.0564x over previous
//
#include <hip/hip_runtime.h>
#include <hip/hip_fp16.h>
#include <math.h>

#define NEG_SLOPE 0.2f

typedef short bf16x8 __attribute__((ext_vector_type(8)));
typedef float f32x4 __attribute__((ext_vector_type(4)));

__device__ __forceinline__ unsigned short f2bf(float f) {
  unsigned int u = __builtin_bit_cast(unsigned int, f);
  u = (u + 0x7fffu + ((u >> 16) & 1u)) >> 16;       // RNE, finite data
  return (unsigned short)u;
}
__device__ __forceinline__ unsigned int pk2bf(float lo, float hi) {
  return (unsigned int)f2bf(lo) | ((unsigned int)f2bf(hi) << 16);
}

// ---------- W1 [512][128] fp32 -> Wt [128][512] bf16 (transposed) ----------
__global__ __launch_bounds__(256) void w1conv_kernel(
    const float* __restrict__ W1, unsigned short* __restrict__ Wt)
{
  int idx = blockIdx.x * 256 + threadIdx.x;   // 0..65535 = k*128+n
  int k = idx >> 7, n = idx & 127;
  Wt[n * 512 + k] = f2bf(W1[idx]);
}

// ---------- GEMM1 (MFMA): h1 = x @ W1, fp16 out, fused a_src1/a_dst1 ----------
// 128x128 tile, BK=64, 4 waves (2x2), mfma_f32_16x16x32_bf16, T2 XOR swizzle.
__global__ __launch_bounds__(256) void gemm1_kernel(
    const float* __restrict__ x, const unsigned short* __restrict__ Wt,
    const float* __restrict__ att_src, const float* __restrict__ att_dst,
    __half* __restrict__ h1, float* __restrict__ a_src, float* __restrict__ a_dst,
    int M)
{
  __shared__ unsigned char Asm[128 * 128];   // 128 rows x 64 bf16 (128 B), swizzled
  __shared__ unsigned char Bsm[128 * 128];
  const int tid  = threadIdx.x;
  const int lane = tid & 63;
  const int wid  = tid >> 6;
  const int wr   = wid >> 1, wc = wid & 1;
  const int row0 = blockIdx.x * 128;

  f32x4 acc[4][4];
  #pragma unroll
  for (int m = 0; m < 4; ++m)
    #pragma unroll
    for (int n = 0; n < 4; ++n) acc[m][n] = (f32x4){0.f, 0.f, 0.f, 0.f};

  const int sr = tid >> 1;             // staging row 0..127
  const int sk = (tid & 1) * 32;       // k-half within BK=64
  const int swz = (sr & 7) << 4;

  for (int k0 = 0; k0 < 512; k0 += 64) {
    // stage A: x[row0+sr][k0+sk .. +31] fp32 -> 32 bf16 (64 B)
    {
      const bool valid = (row0 + sr) < M;
      const float4* src = (const float4*)&x[(size_t)(row0 + sr) * 512 + k0 + sk];
      #pragma unroll
      for (int q = 0; q < 4; ++q) {
        float4 fa = valid ? src[q * 2]     : make_float4(0.f, 0.f, 0.f, 0.f);
        float4 fb = valid ? src[q * 2 + 1] : make_float4(0.f, 0.f, 0.f, 0.f);
        uint4 u = make_uint4(pk2bf(fa.x, fa.y), pk2bf(fa.z, fa.w),
                             pk2bf(fb.x, fb.y), pk2bf(fb.z, fb.w));
        *(uint4*)(Asm + sr * 128 + (((sk + q * 8) * 2) ^ swz)) = u;
      }
    }
    // stage B: Wt[sr][k0+sk .. +31] bf16 (64 B)
    {
      const uint4* src = (const uint4*)&Wt[(size_t)sr * 512 + k0 + sk];
      #pragma unroll
      for (int q = 0; q < 4; ++q)
        *(uint4*)(Bsm + sr * 128 + (((sk + q * 8) * 2) ^ swz)) = src[q];
    }
    __syncthreads();
    #pragma unroll
    for (int ks = 0; ks < 2; ++ks) {
      const int kb = ks * 64 + ((lane >> 4) * 16);
      bf16x8 af[4], bfr[4];
      #pragma unroll
      for (int m = 0; m < 4; ++m) {
        int r = wr * 64 + m * 16 + (lane & 15);
        af[m] = *(const bf16x8*)(Asm + r * 128 + (kb ^ ((r & 7) << 4)));
      }
      #pragma unroll
      for (int n = 0; n < 4; ++n) {
        int r = wc * 64 + n * 16 + (lane & 15);
        bfr[n] = *(const bf16x8*)(Bsm + r * 128 + (kb ^ ((r & 7) << 4)));
      }
      #pragma unroll
      for (int m = 0; m < 4; ++m)
        #pragma unroll
        for (int n = 0; n < 4; ++n)
          acc[m][n] = __builtin_amdgcn_mfma_f32_16x16x32_bf16(af[m], bfr[n], acc[m][n], 0, 0, 0);
    }
    __syncthreads();
  }

  // epilogue: h1 fp16 + per-head a_src/a_dst (head = 16 cols = one n-fragment)
  float asv[4], adv[4];
  #pragma unroll
  for (int n = 0; n < 4; ++n) {
    int col = wc * 64 + n * 16 + (lane & 15);
    asv[n] = att_src[col];
    adv[n] = att_dst[col];
  }
  #pragma unroll
  for (int m = 0; m < 4; ++m) {
    #pragma unroll
    for (int n = 0; n < 4; ++n) {
      const int col  = wc * 64 + n * 16 + (lane & 15);
      const int head = wc * 4 + n;
      #pragma unroll
      for (int e = 0; e < 4; ++e) {
        int row = row0 + wr * 64 + m * 16 + (lane >> 4) * 4 + e;
        float v = acc[m][n][e];
        float ps = v * asv[n], pd = v * adv[n];
        ps += __shfl_xor(ps, 1); pd += __shfl_xor(pd, 1);
        ps += __shfl_xor(ps, 2); pd += __shfl_xor(pd, 2);
        ps += __shfl_xor(ps, 4); pd += __shfl_xor(pd, 4);
        ps += __shfl_xor(ps, 8); pd += __shfl_xor(pd, 8);
        if (row < M) {
          h1[(size_t)row * 128 + col] = __float2half_rn(v);
          if ((lane & 15) == 0) { a_src[row * 8 + head] = ps; a_dst[row * 8 + head] = pd; }
        }
      }
    }
  }
}

// ---------- Counting sort of edges by dst ----------
__global__ __launch_bounds__(256) void hist_kernel(
    const int* __restrict__ ei, int E, int ET, int* __restrict__ cnt)
{
  int e = blockIdx.x * 256 + threadIdx.x;
  if (e >= ET) return;
  int dst = (e < E) ? ei[E + e] : e - E;     // self-loops appended
  atomicAdd(&cnt[dst], 1);
}

__global__ __launch_bounds__(256) void scan_bsum(
    const int* __restrict__ cnt, int* __restrict__ bsum, int M)
{
  __shared__ int sm[256];
  int i = blockIdx.x * 256 + threadIdx.x;
  sm[threadIdx.x] = (i < M) ? cnt[i] : 0;
  __syncthreads();
  for (int o = 128; o; o >>= 1) {
    if (threadIdx.x < o) sm[threadIdx.x] += sm[threadIdx.x + o];
    __syncthreads();
  }
  if (threadIdx.x == 0) bsum[blockIdx.x] = sm[0];
}

__global__ __launch_bounds__(512) void scan_boff(
    const int* __restrict__ bsum, int* __restrict__ boff, int NB)
{
  __shared__ int sm[512];
  int t = threadIdx.x;
  int v = (t < NB) ? bsum[t] : 0;
  sm[t] = v; __syncthreads();
  #pragma unroll
  for (int o = 1; o < 512; o <<= 1) {
    int add = (t >= o) ? sm[t - o] : 0;
    __syncthreads();
    sm[t] += add;
    __syncthreads();
  }
  boff[t] = sm[t] - v;                        // exclusive
}

__global__ __launch_bounds__(256) void scan_final(
    const int* __restrict__ cnt, const int* __restrict__ boff,
    int* __restrict__ startp, int* __restrict__ cursor, int M)
{
  __shared__ int sm[256];
  int t = threadIdx.x;
  int i = blockIdx.x * 256 + t;
  int v = (i < M) ? cnt[i] : 0;
  sm[t] = v; __syncthreads();
  #pragma unroll
  for (int o = 1; o < 256; o <<= 1) {
    int add = (t >= o) ? sm[t - o] : 0;
    __syncthreads();
    sm[t] += add;
    __syncthreads();
  }
  int excl = sm[t] - v + boff[blockIdx.x];
  if (i < M) {
    startp[i] = excl;
    cursor[i] = excl;
    if (i == M - 1) startp[M] = excl + v;
  }
}

__global__ __launch_bounds__(256) void scatter_kernel(
    const int* __restrict__ ei, int E, int ET,
    int* __restrict__ cursor, int* __restrict__ ssrc)
{
  int e = blockIdx.x * 256 + threadIdx.x;
  if (e >= ET) return;
  int src, dst;
  if (e < E) { src = ei[e]; dst = ei[E + e]; }
  else { src = e - E; dst = src; }
  int pos = atomicAdd(&cursor[dst], 1);
  ssrc[pos] = src;
}

// ---------- Layer-1 aggregate: 64 thr/node, 2 ch/thread (half2),
//            fused normalize+bias+ELU, fp16 out ----------
__global__ __launch_bounds__(256) void agg1_kernel(
    const int* __restrict__ startp, const int* __restrict__ ssrc,
    const float* __restrict__ a_s, const float* __restrict__ a_d,
    const __half* __restrict__ h1, const float* __restrict__ b1,
    __half* __restrict__ h1e, int M)
{
  int n = blockIdx.x * 4 + (threadIdx.x >> 6);
  if (n >= M) return;
  const int lane = threadIdx.x & 63;
  const int hd = lane >> 3;                  // channels (2*lane, 2*lane+1) -> head
  const __half2* hp = (const __half2*)h1;
  float ad = a_d[n * 8 + hd];
  int jb = startp[n], je = startp[n + 1];
  float acc0 = 0.f, acc1 = 0.f, ssum = 0.f;
  int j = jb;
  for (; j + 3 < je; j += 4) {               // 4-way MLP for the gathers
    int s0 = ssrc[j], s1 = ssrc[j+1], s2 = ssrc[j+2], s3 = ssrc[j+3];
    float e0 = a_s[s0 * 8 + hd] + ad;
    float e1 = a_s[s1 * 8 + hd] + ad;
    float e2 = a_s[s2 * 8 + hd] + ad;
    float e3 = a_s[s3 * 8 + hd] + ad;
    __half2 g0 = hp[(size_t)s0 * 64 + lane];
    __half2 g1 = hp[(size_t)s1 * 64 + lane];
    __half2 g2 = hp[(size_t)s2 * 64 + lane];
    __half2 g3 = hp[(size_t)s3 * 64 + lane];
    e0 = e0 > 0.f ? e0 : NEG_SLOPE * e0;
    e1 = e1 > 0.f ? e1 : NEG_SLOPE * e1;
    e2 = e2 > 0.f ? e2 : NEG_SLOPE * e2;
    e3 = e3 > 0.f ? e3 : NEG_SLOPE * e3;
    float x0 = __expf(e0), x1 = __expf(e1), x2 = __expf(e2), x3 = __expf(e3);
    float2 f0 = __half22float2(g0), f1 = __half22float2(g1);
    float2 f2 = __half22float2(g2), f3 = __half22float2(g3);
    acc0 = fmaf(x0, f0.x, acc0); acc1 = fmaf(x0, f0.y, acc1);
    acc0 = fmaf(x1, f1.x, acc0); acc1 = fmaf(x1, f1.y, acc1);
    acc0 = fmaf(x2, f2.x, acc0); acc1 = fmaf(x2, f2.y, acc1);
    acc0 = fmaf(x3, f3.x, acc0); acc1 = fmaf(x3, f3.y, acc1);
    ssum += (x0 + x1) + (x2 + x3);
  }
  for (; j < je; ++j) {
    int s0 = ssrc[j];
    float e0 = a_s[s0 * 8 + hd] + ad;
    e0 = e0 > 0.f ? e0 : NEG_SLOPE * e0;
    float x0 = __expf(e0);
    float2 f0 = __half22float2(hp[(size_t)s0 * 64 + lane]);
    acc0 = fmaf(x0, f0.x, acc0); acc1 = fmaf(x0, f0.y, acc1);
    ssum += x0;
  }
  float2 bv = *(const float2*)&b1[lane * 2];
  float v0 = acc0 / ssum + bv.x;             // self-loop guarantees ssum > 0
  float v1 = acc1 / ssum + bv.y;
  v0 = v0 > 0.f ? v0 : expm1f(v0);
  v1 = v1 > 0.f ? v1 : expm1f(v1);
  ((__half2*)h1e)[(size_t)n * 64 + lane] = __floats2half2_rn(v0, v1);
}

// ---------- GEMM2: h2 = h1e @ W2 [N,128]x[128,40], fused a2 dots, fp16 out ----------
__global__ __launch_bounds__(256) void gemm2_kernel(
    const __half* __restrict__ h, const float* __restrict__ W2,
    const float* __restrict__ att_src, const float* __restrict__ att_dst,
    __half* __restrict__ h2, float* __restrict__ a2s, float* __restrict__ a2d,
    int M)
{
  __shared__ float W2s[128 * 40];   // 20 KB, whole W2
  __shared__ float hs[4][128];
  const int tid = threadIdx.x;
  const int lane = tid & 63;
  const int w = tid >> 6;
  const __half2* hp = (const __half2*)h;
  for (int i = tid; i < 128 * 40; i += 256) W2s[i] = W2[i];
  float asv = (lane < 40) ? att_src[lane] : 0.f;
  float adv = (lane < 40) ? att_dst[lane] : 0.f;
  __syncthreads();
  for (int r0 = blockIdx.x * 4; r0 < M; r0 += gridDim.x * 4) {
    {
      int r = r0 + (tid >> 6);
      int cp = tid & 63;
      float2 f = make_float2(0.f, 0.f);
      if (r < M) f = __half22float2(hp[(size_t)r * 64 + cp]);
      hs[tid >> 6][cp * 2] = f.x; hs[tid >> 6][cp * 2 + 1] = f.y;
    }
    __syncthreads();
    const int row = r0 + w;
    float acc = 0.f;
    if (lane < 40) {
      #pragma unroll 8
      for (int k = 0; k < 128; ++k) acc = fmaf(hs[w][k], W2s[k * 40 + lane], acc);
    }
    float ps = acc * asv, pd = acc * adv;
    #pragma unroll
    for (int off = 32; off; off >>= 1) { ps += __shfl_xor(ps, off); pd += __shfl_xor(pd, off); }
    if (row < M) {
      if (lane < 40) h2[(size_t)row * 40 + lane] = __float2half_rn(acc);
      if (lane == 0) { a2s[row] = ps; a2d[row] = pd; }
    }
    __syncthreads();
  }
}

// ---------- Layer-2 aggregate: 32 lanes/node, 2 ch/thread,
//            fused normalize+bias+log_softmax ----------
__global__ __launch_bounds__(256) void agg2_kernel(
    const int* __restrict__ startp, const int* __restrict__ ssrc,
    const float* __restrict__ a2s, const float* __restrict__ a2d,
    const __half* __restrict__ h2, const float* __restrict__ b2,
    float* __restrict__ outp, int M)
{
  int n = blockIdx.x * 8 + (threadIdx.x >> 5);
  if (n >= M) return;
  const int l = threadIdx.x & 31;
  const bool act = l < 20;
  const __half2* hp = (const __half2*)h2;    // row = 20 half2
  float ad = a2d[n];
  int jb = startp[n], je = startp[n + 1];
  float acc0 = 0.f, acc1 = 0.f, ssum = 0.f;
  __half2 z2 = __floats2half2_rn(0.f, 0.f);
  int j = jb;
  for (; j + 3 < je; j += 4) {
    int s0 = ssrc[j], s1 = ssrc[j+1], s2 = ssrc[j+2], s3 = ssrc[j+3];
    float e0 = a2s[s0] + ad;
    float e1 = a2s[s1] + ad;
    float e2 = a2s[s2] + ad;
    float e3 = a2s[s3] + ad;
    __half2 g0 = act ? hp[(size_t)s0 * 20 + l] : z2;
    __half2 g1 = act ? hp[(size_t)s1 * 20 + l] : z2;
    __half2 g2 = act ? hp[(size_t)s2 * 20 + l] : z2;
    __half2 g3 = act ? hp[(size_t)s3 * 20 + l] : z2;
    e0 = e0 > 0.f ? e0 : NEG_SLOPE * e0;
    e1 = e1 > 0.f ? e1 : NEG_SLOPE * e1;
    e2 = e2 > 0.f ? e2 : NEG_SLOPE * e2;
    e3 = e3 > 0.f ? e3 : NEG_SLOPE * e3;
    float x0 = __expf(e0), x1 = __expf(e1), x2 = __expf(e2), x3 = __expf(e3);
    float2 f0 = __half22float2(g0), f1 = __half22float2(g1);
    float2 f2 = __half22float2(g2), f3 = __half22float2(g3);
    acc0 = fmaf(x0, f0.x, acc0); acc1 = fmaf(x0, f0.y, acc1);
    acc0 = fmaf(x1, f1.x, acc0); acc1 = fmaf(x1, f1.y, acc1);
    acc0 = fmaf(x2, f2.x, acc0); acc1 = fmaf(x2, f2.y, acc1);
    acc0 = fmaf(x3, f3.x, acc0); acc1 = fmaf(x3, f3.y, acc1);
    ssum += (x0 + x1) + (x2 + x3);
  }
  for (; j < je; ++j) {
    int s0 = ssrc[j];
    float e0 = a2s[s0] + ad;
    e0 = e0 > 0.f ? e0 : NEG_SLOPE * e0;
    float x0 = __expf(e0);
    float2 f0 = __half22float2(act ? hp[(size_t)s0 * 20 + l] : z2);
    acc0 = fmaf(x0, f0.x, acc0); acc1 = fmaf(x0, f0.y, acc1);
    ssum += x0;
  }
  float v0 = act ? acc0 / ssum + b2[l * 2]     : -1e30f;
  float v1 = act ? acc1 / ssum + b2[l * 2 + 1] : -1e30f;
  // log_softmax over 40 classes held as 2 values x 20 lanes (within 32-lane group)
  float m = fmaxf(v0, v1);
  #pragma unroll
  for (int o = 16; o; o >>= 1) m = fmaxf(m, __shfl_xor(m, o));
  float ex = act ? expf(v0 - m) + expf(v1 - m) : 0.f;
  #pragma unroll
  for (int o = 16; o; o >>= 1) ex += __shfl_xor(ex, o);
  float lg = m + logf(ex);
  if (act) *(float2*)&outp[(size_t)n * 40 + l * 2] = make_float2(v0 - lg, v1 - lg);
}

extern "C" void kernel_launch(void* const* d_in, const int* in_sizes, int n_in,
                              void* d_out, int out_size, void* d_ws, size_t ws_size,
                              hipStream_t stream)
{
  const float* x   = (const float*)d_in[0];
  const int*   ei  = (const int*)d_in[1];
  const float* W1  = (const float*)d_in[2];
  const float* as1 = (const float*)d_in[3];
  const float* ad1 = (const float*)d_in[4];
  const float* b1  = (const float*)d_in[5];
  const float* W2  = (const float*)d_in[6];
  const float* as2 = (const float*)d_in[7];
  const float* ad2 = (const float*)d_in[8];
  const float* b2  = (const float*)d_in[9];
  float* outp = (float*)d_out;

  const int M  = in_sizes[0] / 512;    // 100000
  const int E  = in_sizes[1] / 2;      // 1600000
  const int ET = E + M;                // + self loops
  const int NB = (M + 255) / 256;      // scan blocks (391)

  __half* h1  = (__half*)d_ws;              // M*128 fp16
  __half* h1e = h1 + (size_t)M * 128;       // M*128 fp16
  __half* h2  = h1e + (size_t)M * 128;      // M*40 fp16
  float* a_s1 = (float*)(h2 + (size_t)M * 40);
  float* a_d1 = a_s1 + (size_t)M * 8;
  float* a2s  = a_d1 + (size_t)M * 8;
  float* a2d  = a2s + M;
  int* cnt    = (int*)(a2d + M);            // M
  int* startp = cnt + M;                    // M+1
  int* cursor = startp + (M + 1);           // M
  int* bsum   = cursor + M;                 // NB
  int* boff   = bsum + NB;                  // 512
  int* ssrc   = boff + 512;                 // ET
  unsigned short* Wt = (unsigned short*)(ssrc + ET);  // 128*512 bf16

  hipMemsetAsync(cnt, 0, (size_t)M * sizeof(int), stream);

  // edge sort by dst (reused by both layers)
  hist_kernel<<<(ET + 255) / 256, 256, 0, stream>>>(ei, E, ET, cnt);
  scan_bsum<<<NB, 256, 0, stream>>>(cnt, bsum, M);
  scan_boff<<<1, 512, 0, stream>>>(bsum, boff, NB);
  scan_final<<<NB, 256, 0, stream>>>(cnt, boff, startp, cursor, M);
  scatter_kernel<<<(ET + 255) / 256, 256, 0, stream>>>(ei, E, ET, cursor, ssrc);

  // layer 1
  w1conv_kernel<<<256, 256, 0, stream>>>(W1, Wt);
  gemm1_kernel<<<(M + 127) / 128, 256, 0, stream>>>(x, Wt, as1, ad1, h1, a_s1, a_d1, M);
  agg1_kernel<<<(M + 3) / 4, 256, 0, stream>>>(startp, ssrc, a_s1, a_d1, h1, b1, h1e, M);

  // layer 2
  gemm2_kernel<<<1024, 256, 0, stream>>>(h1e, W2, as2, ad2, h2, a2s, a2d, M);
  agg2_kernel<<<(M + 7) / 8, 256, 0, stream>>>(startp, ssrc, a2s, a2d, h2, b2, outp, M);
}